// Round 6
// baseline (558.498 us; speedup 1.0000x reference)
//
#include <hip/hip_runtime.h>
#include <cmath>

#define N_PTS 200000
#define HD 64
#define CD 128
#define KEEP 63

typedef __bf16 bf16;
typedef __bf16 bf16x4 __attribute__((ext_vector_type(4)));
typedef __bf16 bf16x8 __attribute__((ext_vector_type(8)));
typedef float f32x4 __attribute__((ext_vector_type(4)));
typedef float f32x16 __attribute__((ext_vector_type(16)));

__device__ __forceinline__ float elu_f(float v) {
    return v > 0.f ? v : __expf(v) - 1.f;
}

// ---------------------------------------------------------------------------
// K0: prep weights + zero-page.
//   WbT fragment-major: frag f=(i>>4)*2+(o>>5), lane=((i>>3)&1)*32+(o&31), e=i&7
//   WaT fragment-major (same scheme, 16 frags of 512)
//   WcT2 fragment-major Wc for the k_conv epilogue
//   zp re-zeroed every call (ws is poisoned 0xAA).
// ---------------------------------------------------------------------------
__global__ __launch_bounds__(256) void k_prep(const float* __restrict__ Wb,
                                              const float* __restrict__ Wc,
                                              const float* __restrict__ Wa,
                                              bf16* __restrict__ WbT,
                                              bf16* __restrict__ WcT2,
                                              bf16* __restrict__ WaT,
                                              bf16* __restrict__ zp) {
    int idx = blockIdx.x * 256 + threadIdx.x;
    if (idx < KEEP * HD * HD) {
        int k = idx >> 12;
        int rem = idx & 4095;
        int o = rem >> 6, i = rem & 63;     // o = out-row, i = in-col
        int dst = ((i >> 4) * 2 + (o >> 5)) * 512 +
                  (((i >> 3) & 1) * 32 + (o & 31)) * 8 + (i & 7);
        WbT[(k << 12) + dst] = (bf16)Wb[(k * HD + i) * HD + o];
        return;
    }
    int e = idx - KEEP * HD * HD;
    if (e < CD * HD) {           // WcT2 fragment-major
        int c = e >> 6, h = e & 63;      // c: 0..127, h: 0..63
        int dst = ((c >> 5) * 4 + (h >> 4)) * 512 +
                  ((((h >> 3) & 1) * 32) + (c & 31)) * 8 + (h & 7);
        WcT2[dst] = (bf16)Wc[h * CD + c];
        return;
    }
    e -= CD * HD;
    if (e < HD * CD) {           // WaT, fragment-major
        int o = e >> 7, c = e & 127;
        int dst = ((c >> 4) * 2 + (o >> 5)) * 512 +
                  (((c >> 3) & 1) * 32 + (o & 31)) * 8 + (c & 7);
        WaT[dst] = (bf16)Wa[c * HD + o];
        return;
    }
    e -= HD * CD;
    if (e < 64) zp[e] = (bf16)0.f;
}

// ---------------------------------------------------------------------------
// K1: f[n][h] = elu( elu(x[n]+y[n]) @ Wa ), bf16.  (round-1-proven, unchanged)
// ---------------------------------------------------------------------------
__global__ __launch_bounds__(256, 4) void k_stage1(const float* __restrict__ x,
                                                   const float* __restrict__ y,
                                                   const bf16* __restrict__ WaT,
                                                   bf16* __restrict__ f) {
    __shared__ bf16 pbuf[4][32 * 64];   // 16 KB, per-wave transpose buffer
    int tid = threadIdx.x;
    int wave = tid >> 6;
    int lane = tid & 63;
    int l31 = lane & 31;
    int half = lane >> 5;
    int pbase_w = blockIdx.x * 128 + wave * 32;
    int p = pbase_w + l31;
    int pc = p < N_PTS ? p : N_PTS - 1;     // clamp loads; stores guarded

    const float* xr = x + (size_t)pc * CD;
    const float* yr = y + (size_t)pc * CD;

    f32x16 acc[2];
#pragma unroll
    for (int mt = 0; mt < 2; mt++)
#pragma unroll
        for (int r = 0; r < 16; r++) acc[mt][r] = 0.f;

    f32x4 xa[2], xb[2], ya[2], yb[2];
    {
        int c0 = half * 8;
        xa[0] = *(const f32x4*)(xr + c0);
        xb[0] = *(const f32x4*)(xr + c0 + 4);
        ya[0] = *(const f32x4*)(yr + c0);
        yb[0] = *(const f32x4*)(yr + c0 + 4);
    }
#pragma unroll
    for (int ks = 0; ks < 8; ks++) {
        int cur = ks & 1, nxt = cur ^ 1;
        bf16x8 a0 = *(const bf16x8*)(WaT + (ks * 2 + 0) * 512 + lane * 8);
        bf16x8 a1 = *(const bf16x8*)(WaT + (ks * 2 + 1) * 512 + lane * 8);
        __builtin_amdgcn_sched_barrier(0);
        if (ks < 7) {
            int c0 = half * 8 + (ks + 1) * 16;
            xa[nxt] = *(const f32x4*)(xr + c0);
            xb[nxt] = *(const f32x4*)(xr + c0 + 4);
            ya[nxt] = *(const f32x4*)(yr + c0);
            yb[nxt] = *(const f32x4*)(yr + c0 + 4);
        }
        bf16x8 bv;
#pragma unroll
        for (int jj = 0; jj < 4; jj++) {
            bv[jj]     = (bf16)elu_f(xa[cur][jj] + ya[cur][jj]);
            bv[4 + jj] = (bf16)elu_f(xb[cur][jj] + yb[cur][jj]);
        }
        acc[0] = __builtin_amdgcn_mfma_f32_32x32x16_bf16(a0, bv, acc[0], 0, 0, 0);
        acc[1] = __builtin_amdgcn_mfma_f32_32x32x16_bf16(a1, bv, acc[1], 0, 0, 0);
        __builtin_amdgcn_sched_barrier(0);
    }

    bf16* pb = pbuf[wave];
#pragma unroll
    for (int mt = 0; mt < 2; mt++) {
#pragma unroll
        for (int q = 0; q < 4; q++) {
            bf16x4 v;
#pragma unroll
            for (int jj = 0; jj < 4; jj++)
                v[jj] = (bf16)elu_f(acc[mt][q * 4 + jj]);
            int chunk = mt * 4 + q;   // h = chunk*8 + 4*half + j
            *(bf16x4*)&pb[l31 * 64 + ((chunk ^ (l31 & 7)) * 8) + 4 * half] = v;
        }
    }
#pragma unroll
    for (int qq = 0; qq < 4; qq++) {
        int t = lane + 64 * qq;          // 0..255 chunk ids
        int row = t >> 3, ch = t & 7;
        int pos = ch ^ (row & 7);
        bf16x8 v = *(const bf16x8*)&pb[row * 64 + pos * 8];
        int pp = pbase_w + row;
        if (pp < N_PTS)
            *(bf16x8*)(f + (size_t)pp * HD + ch * 8) = v;
    }
}

// ---------------------------------------------------------------------------
// K2: conv + fused epilogue.  ROUND-6: 64 pts/wave (256 pts/block, grid 782).
//   Round-5 skeleton (LDS-shared A dbuf + raw s_barrier + counted vmcnt +
//   group-of-8 gather + swizzled bounce) with DOUBLE the work per barrier:
//     - 16 MFMA/wave/substep (2 point-sets share each A-frag ds_read)
//     - sequential substep-slots per CU halve (grid 1563 -> 782)
//     - A global+LDS traffic per point halves
//   Round-5's wall was amortization: ~3.2k cyc/slot for 512 cyc of MFMA.
//   Pipeline slacks (all waits counted): gathers 2 substeps (>=3k cyc >> L3),
//   idx depth-2 (use 4 substeps after load >> 900cyc HBM), stage A consumed
//   next substep.  Race audit identical to round 5 (only lds_a is
//   cross-wave; bounce is per-wave, in-order DS pipe).
//   Register budget: acc 64 AGPR + gather 64 + idx 16 + stage 8 + temps,
//   under the (256,2)=256 cap -> no spill (round-3 lesson).
// ---------------------------------------------------------------------------
struct GR8 { bf16x8 v[8]; };

__global__ __launch_bounds__(256, 2) void k_conv(const bf16* __restrict__ f,
                                                 const int* __restrict__ nidx,
                                                 const bf16* __restrict__ WbT,
                                                 const bf16* __restrict__ WcT2,
                                                 const bf16* __restrict__ zp,
                                                 const float* __restrict__ x,
                                                 float* __restrict__ out) {
    __shared__ bf16 lds_a[2][4096];      // 16 KB: A(k) double buffer, frag-major
    __shared__ bf16 bounce[4][64 * 64];  // 32 KB: per-wave 8 KB gather buf

    int tid = threadIdx.x;
    int wave = tid >> 6;
    int lane = tid & 63;
    int l31 = lane & 31;
    int half = lane >> 5;
    int g8 = lane >> 3;        // group id 0..7 (row within gather inst)
    int l7 = lane & 7;         // lane-in-group (16B chunk of the row)
    int pbase = blockIdx.x * 256 + wave * 64;

    bf16* pb = bounce[wave];

    f32x16 acc[2][2];          // [mt][set]
#pragma unroll
    for (int a = 0; a < 2; a++)
#pragma unroll
        for (int b = 0; b < 2; b++)
#pragma unroll
            for (int r = 0; r < 16; r++) acc[a][b][r] = 0.f;

    // idx for gather-inst i (i=0..7) of offset k: point = pbase + i*8 + g8
    auto ldidx8 = [&](int k, int i) -> int {
        int pp = pbase + i * 8 + g8;
        return (k < KEEP && pp < N_PTS) ? nidx[(size_t)k * N_PTS + pp] : -1;
    };
    auto gaddr = [&](int iv) -> const bf16* {
        return iv >= 0 ? f + (size_t)iv * HD + l7 * 8 : zp + l7 * 8;
    };
    auto gather8 = [&](GR8& g, const int (&iv)[8]) {
#pragma unroll
        for (int i = 0; i < 8; i++)
            g.v[i] = *(const bf16x8*)gaddr(iv[i]);
    };
    // scatter gathered rows into bounce, XOR-swizzled: chunk c of row r at
    // position (c ^ (r&7)); here c=l7, r = i*8+g8 so r&7 = g8.
    auto dswrite8 = [&](const GR8& g) {
#pragma unroll
        for (int i = 0; i < 8; i++) {
            int r = i * 8 + g8;                        // row 0..63
            *(bf16x8*)&pb[r * 64 + ((l7 ^ g8) * 8)] = g.v[i];
        }
    };
    // stage A(k): wave w covers frags 2w, 2w+1 (2 x 1KB coalesced wave-loads)
    auto stageIssue = [&](int k, bf16x8& s0, bf16x8& s1) {
        const bf16* wk = WbT + ((size_t)k << 12) + wave * 1024 + lane * 8;
        s0 = *(const bf16x8*)(wk);
        s1 = *(const bf16x8*)(wk + 512);
    };
    auto stageWrite = [&](int kb, const bf16x8& s0, const bf16x8& s1) {
        bf16* d = &lds_a[kb][wave * 1024 + lane * 8];
        *(bf16x8*)(d) = s0;
        *(bf16x8*)(d + 512) = s1;
    };
    auto mfma16 = [&](int kb) {
        const bf16* A = lds_a[kb];
#pragma unroll
        for (int ks = 0; ks < 4; ks++) {
            bf16x8 a0 = *(const bf16x8*)&A[(ks * 2 + 0) * 512 + lane * 8];
            bf16x8 a1 = *(const bf16x8*)&A[(ks * 2 + 1) * 512 + lane * 8];
            int ci = ks * 2 + half;
#pragma unroll
            for (int set = 0; set < 2; set++) {
                int r = set * 32 + l31;
                bf16x8 fb = *(const bf16x8*)&pb[r * 64 + ((ci ^ (l31 & 7)) * 8)];
                acc[0][set] = __builtin_amdgcn_mfma_f32_32x32x16_bf16(a0, fb, acc[0][set], 0, 0, 0);
                acc[1][set] = __builtin_amdgcn_mfma_f32_32x32x16_bf16(a1, fb, acc[1][set], 0, 0, 0);
            }
        }
    };
    // substep k: issue stage A(k+1) + gather rows k+2 + idx(k+4); compute k
    // from lds_a[k&1] + bounce; write bounce rows k+1 and lds_a[(k+1)&1].
    auto substep = [&](int k, GR8& gfill, const GR8& gwrite, int (&slot)[8]) {
        bf16x8 sA0, sA1;
        stageIssue(k + 1, sA0, sA1);                   // 2 loads (oldest)
        __builtin_amdgcn_sched_barrier(0);
        gather8(gfill, slot);                          // 8 loads
#pragma unroll
        for (int i = 0; i < 8; i++) slot[i] = ldidx8(k + 4, i);   // 8 loads
        __builtin_amdgcn_sched_barrier(0);
        mfma16(k & 1);                                 // ds_read + MFMA
        __builtin_amdgcn_sched_barrier(0);
        dswrite8(gwrite);                              // vmcnt counted
        stageWrite((k + 1) & 1, sA0, sA1);             // vmcnt(16), counted
        asm volatile("s_waitcnt lgkmcnt(0)" ::: "memory");
        __builtin_amdgcn_s_barrier();
        __builtin_amdgcn_sched_barrier(0);
    };

    // ---- prologue ----
    int s0[8], s1[8];          // rotating idx slots, depth-2 (even/odd substeps)
#pragma unroll
    for (int i = 0; i < 8; i++) s0[i] = ldidx8(2, i);
#pragma unroll
    for (int i = 0; i < 8; i++) s1[i] = ldidx8(3, i);
    GR8 ge, go;
    {
        int i0[8], i1[8];
#pragma unroll
        for (int i = 0; i < 8; i++) i0[i] = ldidx8(0, i);
#pragma unroll
        for (int i = 0; i < 8; i++) i1[i] = ldidx8(1, i);
        GR8 g0;
        gather8(g0, i0);        // rows k=0
        gather8(go, i1);        // rows k=1 (bounce-written at substep 0)
        bf16x8 sA0, sA1;
        stageIssue(0, sA0, sA1);
        dswrite8(g0);           // bounce holds k=0
        stageWrite(0, sA0, sA1);
        asm volatile("s_waitcnt lgkmcnt(0)" ::: "memory");
        __builtin_amdgcn_s_barrier();
        __builtin_amdgcn_sched_barrier(0);
    }

    // ---- main loop: k = 0..61 (31 even/odd pairs) ----
    for (int j = 0; j < 31; j++) {
        substep(2 * j,     ge, go, s0);
        substep(2 * j + 1, go, ge, s1);
    }
    // ---- tail: k = 62 (lds_a[0] staged at substep 61; bounce holds rows 62)
    mfma16(0);

    // ---- epilogue: out[p][c] = x[p][c] + elu(acc)^T @ Wc ----
    // P-transpose through bounce (per-wave, in-order DS, no barrier), Wc
    // frags direct from global (L2-hot, coalesced 1KB reads).
#pragma unroll
    for (int pt = 0; pt < 2; pt++) {
#pragma unroll
        for (int mt = 0; mt < 2; mt++) {
#pragma unroll
            for (int q = 0; q < 4; q++) {
                bf16x4 v;
#pragma unroll
                for (int jj = 0; jj < 4; jj++)
                    v[jj] = (bf16)elu_f(acc[mt][pt][q * 4 + jj]);
                int chunk = mt * 4 + q;
                *(bf16x4*)&pb[l31 * 64 + ((chunk ^ (l31 & 7)) * 8) + 4 * half] = v;
            }
        }
        bf16x8 pa[4];
#pragma unroll
        for (int ks = 0; ks < 4; ks++) {
            int ci = 2 * ks + half;
            pa[ks] = *(const bf16x8*)&pb[l31 * 64 + ((ci ^ (l31 & 7)) * 8)];
        }
#pragma unroll
        for (int ct = 0; ct < 4; ct++) {
            f32x16 o;
#pragma unroll
            for (int r = 0; r < 16; r++) o[r] = 0.f;
            int cc = ct * 32 + l31;
#pragma unroll
            for (int ks = 0; ks < 4; ks++) {
                bf16x8 bw = *(const bf16x8*)(WcT2 + ((ct * 4 + ks) << 9) + lane * 8);
                o = __builtin_amdgcn_mfma_f32_32x32x16_bf16(pa[ks], bw, o, 0, 0, 0);
            }
            int prow_base = pbase + pt * 32 + 4 * half;
#pragma unroll
            for (int r = 0; r < 16; r++) {
                int prow = prow_base + (r & 3) + 8 * (r >> 2);
                if (prow < N_PTS) {
                    size_t off = (size_t)prow * CD + cc;
                    out[off] = x[off] + o[r];
                }
            }
        }
    }
}

// ---------------------------------------------------------------------------
extern "C" void kernel_launch(void* const* d_in, const int* in_sizes, int n_in,
                              void* d_out, int out_size, void* d_ws, size_t ws_size,
                              hipStream_t stream) {
    const float* x  = (const float*)d_in[0];
    const float* y  = (const float*)d_in[1];
    const float* Wa = (const float*)d_in[2];
    const float* Wb = (const float*)d_in[3];
    const float* Wc = (const float*)d_in[4];
    const int* nidx = (const int*)d_in[5];
    float* out = (float*)d_out;

    char* ws = (char*)d_ws;
    bf16* f    = (bf16*)ws;                           // 200192*64*2 = 25,624,576 B
    bf16* WbT  = (bf16*)(ws + 25624576);              // 63*4096*2   =    516,096 B
    bf16* WcT2 = (bf16*)(ws + 25624576 + 516096);     // 8192*2      =     16,384 B
    bf16* WaT  = (bf16*)(ws + 25624576 + 516096 + 16384);   // 8192*2 = 16,384 B
    bf16* zp   = (bf16*)(ws + 25624576 + 516096 + 16384 + 16384);  // 128 B zeros

    k_prep<<<1073, 256, 0, stream>>>(Wb, Wc, Wa, WbT, WcT2, WaT, zp);
    k_stage1<<<1564, 256, 0, stream>>>(x, y, WaT, f);
    k_conv<<<782, 256, 0, stream>>>(f, nidx, WbT, WcT2, zp, x, out);
}